// Round 1
// baseline (72.143 us; speedup 1.0000x reference)
//
#include <hip/hip_runtime.h>

// B=256, N=25, C=256, H/2=128.
// Telescoping: edge_feat[b,i,j,:] = src[b,j]-src[b,i]  =>  u = src @ W1^T (f16 MFMA).
// PReLU identity: max(d,0)=max(uj,ui)-ui =>
//   out[i,j] = (1-a)*M[i,j] + a*s_j - s_i,  M[i,j]=sum_h w2*max(uj,ui) (symmetric),
//   s_i = sum_h w2*u_i; diagonal exactly 0.  300 upper-tri pairs only.
//
// R10: W1 no longer goes through LDS at all. Each lane's MFMA B-fragment is a
// statically-known 8-float slice of one W1 row (W1[hcol][kt*32+quad*8..+8]) --
// the lane that loads it is the lane that consumes it, so the v9 LDS round
// trip (16 ds_write_b64 + 8 ds_read_b128 per thread + barrier dependency) was
// pure redistribution overhead. Now: 16 dwordx4 direct loads issued up-front
// (one vmcnt wait), in-register RNE f32->f16 convert (bitwise-identical
// numerics to v9), fragments live in VGPRs across phase 1. Only src gates the
// barrier. LDS drops 88 KB -> ~21 KB.
#define NJ   25
#define CIN  256
#define HH   128
#define SS   264   // src LDS row stride in SHORTS (528 B = 33*16, 16B-aligned rows)
#define US   136   // u16 row stride in shorts (272 B)

typedef _Float16 h2  __attribute__((ext_vector_type(2)));
typedef _Float16 h8f __attribute__((ext_vector_type(8)));
typedef __attribute__((ext_vector_type(4))) float f32x4;

__device__ __forceinline__ unsigned short f2h_bits(float f) {
    union { _Float16 h; unsigned short u; } v; v.h = (_Float16)f; return v.u;
}
__device__ __forceinline__ unsigned pack2h(float a, float b) {
    return (unsigned)f2h_bits(a) | ((unsigned)f2h_bits(b) << 16);
}
__device__ __forceinline__ h2 as_h2(unsigned u) {
    union { unsigned u; h2 h; } v; v.u = u; return v.h;
}

__global__ __launch_bounds__(512) void fused_edge_mlp_v10(
    const float* __restrict__ src,   // [B,25,256]
    const float* __restrict__ W1,    // [128,256]
    const float* __restrict__ Aarr,  // [1] alpha
    const float* __restrict__ W2,    // [128]
    float* __restrict__ out)         // [B,25,25]
{
    __shared__ unsigned short s_lds[NJ * SS];   // src[b] as f16 (13.2 KB)
    __shared__ unsigned short u16[NJ * US];     // u as f16 (6.8 KB)
    __shared__ unsigned w2s[HH / 2];            // packed f16 W2 (256 B)
    __shared__ float s_s[NJ];                   // s_i

    const int b    = blockIdx.x;
    const int t    = threadIdx.x;
    const int w    = t >> 6;
    const int lane = t & 63;
    const int ln15 = lane & 15;
    const int quad = lane >> 4;
    const int hcol = w * 16 + ln15;

    // ---- Phase 0a: issue W1 B-fragment loads direct to registers ----
    // lane (w, ln15, quad) owns W1[hcol][kt*32 + quad*8 .. +8] for kt=0..7
    // (exactly the operand it feeds to MFMA in phase 1). 16 dwordx4, all
    // independent, issued before anything blocks on them.
    const float* w1row = W1 + (size_t)hcol * CIN + quad * 8;
    float4 w1r[16];
    #pragma unroll
    for (int kt = 0; kt < 8; ++kt) {
        w1r[2 * kt]     = *(const float4*)(w1row + kt * 32);
        w1r[2 * kt + 1] = *(const float4*)(w1row + kt * 32 + 4);
    }

    // ---- Phase 0b: src[b] -> LDS f16 (coalesced, 1600 float4 chunks) ----
    const float4* s4 = (const float4*)(src + (size_t)b * NJ * CIN);
    float4 sv[4];
    #pragma unroll
    for (int it = 0; it < 4; ++it) {
        const int idx = t + it * 512;
        if (idx < NJ * CIN / 4) sv[it] = s4[idx];
    }
    // W2: 64 packed dwords
    if (t < HH / 2) w2s[t] = pack2h(W2[2 * t], W2[2 * t + 1]);

    #pragma unroll
    for (int it = 0; it < 4; ++it) {
        const int idx = t + it * 512;
        if (idx < NJ * CIN / 4) {
            const int n = idx >> 6, k4 = idx & 63;
            *(uint2*)&s_lds[n * SS + k4 * 4] =
                make_uint2(pack2h(sv[it].x, sv[it].y), pack2h(sv[it].z, sv[it].w));
        }
    }

    // ---- Phase 0c: convert W1 regs -> f16 fragments (VALU, overlaps barrier) ----
    h8f bfr[8];
    #pragma unroll
    for (int kt = 0; kt < 8; ++kt) {
        const float4 lo = w1r[2 * kt], hi = w1r[2 * kt + 1];
        h8f f;
        f[0] = (_Float16)lo.x; f[1] = (_Float16)lo.y;
        f[2] = (_Float16)lo.z; f[3] = (_Float16)lo.w;
        f[4] = (_Float16)hi.x; f[5] = (_Float16)hi.y;
        f[6] = (_Float16)hi.z; f[7] = (_Float16)hi.w;
        bfr[kt] = f;
    }
    __syncthreads();

    // ---- Phase 1: u = src_f16 @ W1_f16^T, A from LDS (b128), B from regs ----
    {
        const int r1    = 16 + ln15;
        const bool r1ok = (r1 < NJ);
        const int cbase = quad * 8;

        f32x4 acc0 = {0.f, 0.f, 0.f, 0.f};
        f32x4 acc1 = {0.f, 0.f, 0.f, 0.f};
        #pragma unroll
        for (int kt = 0; kt < 8; ++kt) {
            const int co = kt * 32 + cbase;
            h8f a0 = *(const h8f*)&s_lds[ln15 * SS + co];
            h8f a1 = {};
            if (r1ok) a1 = *(const h8f*)&s_lds[r1 * SS + co];
            acc0 = __builtin_amdgcn_mfma_f32_16x16x32_f16(a0, bfr[kt], acc0, 0, 0, 0);
            acc1 = __builtin_amdgcn_mfma_f32_16x16x32_f16(a1, bfr[kt], acc1, 0, 0, 0);
        }

        // D layout: col(h)=lane&15, row(m)=quad*4+reg
        #pragma unroll
        for (int r = 0; r < 4; ++r) {
            int m0 = quad * 4 + r;
            if (m0 < NJ) u16[m0 * US + hcol] = f2h_bits(acc0[r]);
            int m1 = 16 + quad * 4 + r;
            if (m1 < NJ) u16[m1 * US + hcol] = f2h_bits(acc1[r]);
        }
    }
    __syncthreads();

    // ---- Phase 2a: pair lanes compute M; side lanes compute s_i ----
    const float alpha = Aarr[0];
    float* outb = out + (size_t)b * (NJ * NJ);
    const uint4* w2v = (const uint4*)w2s;   // uniform -> LDS broadcast

    float M = 0.f;
    int i = 0, j = 0;
    if (t < 300) {
        i = (int)((49.0f - sqrtf(2401.0f - 8.0f * (float)t)) * 0.5f);
        {   // fp-safety clamp
            int Si = (49 * i - i * i) >> 1;
            if (t < Si) { --i; }
            else { int Sn = (49 * (i + 1) - (i + 1) * (i + 1)) >> 1; if (t >= Sn) ++i; }
        }
        const int S = (49 * i - i * i) >> 1;
        j = t - S + i + 1;

        const uint4* ujp = (const uint4*)(u16 + j * US);
        const uint4* uip = (const uint4*)(u16 + i * US);
        #pragma unroll
        for (int h8 = 0; h8 < 16; ++h8) {
            uint4 a = ujp[h8], c = uip[h8], ww = w2v[h8];
            h2 mx;
            mx = __builtin_elementwise_max(as_h2(a.x), as_h2(c.x));
            M  = __builtin_amdgcn_fdot2(mx, as_h2(ww.x), M, false);
            mx = __builtin_elementwise_max(as_h2(a.y), as_h2(c.y));
            M  = __builtin_amdgcn_fdot2(mx, as_h2(ww.y), M, false);
            mx = __builtin_elementwise_max(as_h2(a.z), as_h2(c.z));
            M  = __builtin_amdgcn_fdot2(mx, as_h2(ww.z), M, false);
            mx = __builtin_elementwise_max(as_h2(a.w), as_h2(c.w));
            M  = __builtin_amdgcn_fdot2(mx, as_h2(ww.w), M, false);
        }
    } else if (t < 300 + NJ) {
        const int r = t - 300;
        const uint4* up = (const uint4*)(u16 + r * US);
        float s = 0.f;
        #pragma unroll
        for (int h8 = 0; h8 < 16; ++h8) {
            uint4 a = up[h8], ww = w2v[h8];
            s = __builtin_amdgcn_fdot2(as_h2(a.x), as_h2(ww.x), s, false);
            s = __builtin_amdgcn_fdot2(as_h2(a.y), as_h2(ww.y), s, false);
            s = __builtin_amdgcn_fdot2(as_h2(a.z), as_h2(ww.z), s, false);
            s = __builtin_amdgcn_fdot2(as_h2(a.w), as_h2(ww.w), s, false);
        }
        s_s[r] = s;
    }
    __syncthreads();

    // ---- Phase 2b: combine and write ----
    if (t < 300) {
        const float sj = s_s[j], si = s_s[i];
        const float Mw = (1.f - alpha) * M;
        outb[i * NJ + j] = Mw + alpha * sj - si;
        outb[j * NJ + i] = Mw + alpha * si - sj;
    } else if (t >= 325 && t < 350) {
        const int r = t - 325;
        outb[r * (NJ + 1)] = 0.f;     // diagonal: d=0 -> prelu=0 exactly
    }
}

extern "C" void kernel_launch(void* const* d_in, const int* in_sizes, int n_in,
                              void* d_out, int out_size, void* d_ws, size_t ws_size,
                              hipStream_t stream) {
    // inputs: 0=src, 1=heads, 2=ends, 3=pair_ids (unused: telescoping), 4=W1, 5=alpha, 6=W2
    const float* src   = (const float*)d_in[0];
    const float* W1    = (const float*)d_in[4];
    const float* alpha = (const float*)d_in[5];
    const float* W2    = (const float*)d_in[6];
    float* out = (float*)d_out;

    const int B = in_sizes[0] / (NJ * CIN);   // 256
    fused_edge_mlp_v10<<<B, 512, 0, stream>>>(src, W1, alpha, W2, out);
}